// Round 6
// baseline (485.282 us; speedup 1.0000x reference)
//
#include <hip/hip_runtime.h>
#include <stdint.h>

typedef __bf16 bf16x8 __attribute__((ext_vector_type(8)));
typedef float f32x4 __attribute__((ext_vector_type(4)));
typedef unsigned short ushort_t;

#define NPARENT 60000
#define NOUT (NPARENT*8)          // 480000 output rows
#define ZPB (NPARENT<<10)         // zero-parent byte base (8 zero rows)
#define TBL_N (66*66*66)          // parent table, coords shifted +1
#define NBIN 4096                 // 16^3 Morton bins of 4^3 cells

static constexpr size_t OFF_TABLE = 0;
static constexpr size_t OFF_CS    = 1149984;                    // = TBL_N*4, 16-aligned
static constexpr size_t OFF_Y     = OFF_CS + 960000;            // (NOUT+8)*128 bytes
static constexpr size_t OFF_HIST  = OFF_Y;                      // alias, pre-k_up only
static constexpr size_t OFF_CNT   = OFF_Y + 16384;
static constexpr size_t YSZ       = (size_t)(NOUT+8)*128;
static constexpr size_t OFF_Z     = OFF_Y + YSZ;
static constexpr size_t OFF_FEATB = OFF_Z + YSZ;
static constexpr size_t OFF_WUPF  = OFF_FEATB + (size_t)NPARENT*128;
static constexpr size_t OFF_W1F   = OFF_WUPF + (size_t)8*8192;
static constexpr size_t OFF_W2F   = OFF_W1F + (size_t)27*8192;
static constexpr size_t WS_NEED   = OFF_W2F + (size_t)27*8192;  // ~133.2 MB

__device__ __forceinline__ ushort_t f2bf(float x) {   // RNE float->bf16
  uint32_t u = __float_as_uint(x);
  u += 0x7fffu + ((u >> 16) & 1u);
  return (ushort_t)(u >> 16);
}

__device__ __forceinline__ int binof(int x, int y, int z) {  // 12-bit Morton of 4-cell bins
  int bx = x >> 2, by = y >> 2, bz = z >> 2, m = 0;
  #pragma unroll
  for (int b = 0; b < 4; ++b)
    m |= (((bx>>b)&1) << (3*b+2)) | (((by>>b)&1) << (3*b+1)) | (((bz>>b)&1) << (3*b));
  return m;
}

__device__ __forceinline__ void gl2lds16(const void* g, void* l) {
  __builtin_amdgcn_global_load_lds(
      (const __attribute__((address_space(1))) uint32_t*)g,
      (__attribute__((address_space(3))) uint32_t*)l, 16, 0, 0);
}

__global__ void k_zero(ushort_t* y, ushort_t* z) {   // zero-parent: 8 rows each
  int t = threadIdx.x;
  if (t < 512) y[(size_t)NOUT*64 + t] = 0;
  else         z[(size_t)NOUT*64 + (t-512)] = 0;
}

__global__ void k_hist(const int* __restrict__ coords, int* __restrict__ hist) {
  int i = blockIdx.x*blockDim.x + threadIdx.x;
  if (i >= NPARENT) return;
  atomicAdd(&hist[binof(coords[3*i], coords[3*i+1], coords[3*i+2])], 1);
}

__global__ void k_scan(const int* __restrict__ hist, int* __restrict__ cnt) {
  __shared__ int s[256];
  int t = threadIdx.x;
  int loc[16], sum = 0;
  #pragma unroll
  for (int j=0;j<16;++j){ loc[j]=hist[t*16+j]; sum+=loc[j]; }
  s[t]=sum;
  __syncthreads();
  if (t==0){ int a=0; for (int i=0;i<256;++i){ int v=s[i]; s[i]=a; a+=v; } }
  __syncthreads();
  int a=s[t];
  #pragma unroll
  for (int j=0;j<16;++j){ cnt[t*16+j]=a; a+=loc[j]; }
}

__global__ void k_rank(const int* __restrict__ coords, int* __restrict__ cnt,
                       int4* __restrict__ cs, int* __restrict__ tbl) {
  int i = blockIdx.x*blockDim.x + threadIdx.x;
  if (i >= NPARENT) return;
  int x = coords[3*i], y = coords[3*i+1], z = coords[3*i+2];
  int r = atomicAdd(&cnt[binof(x,y,z)], 1);
  cs[r] = make_int4(x, y, z, i);
  tbl[((x+1)*66 + (y+1))*66 + (z+1)] = r;
}

__global__ void k_feats_bf16(const float4* __restrict__ f, const int4* __restrict__ cs,
                             ushort_t* __restrict__ o, int total) {
  int t = blockIdx.x*blockDim.x + threadIdx.x;
  if (t >= total) return;
  int p = t >> 4, q = t & 15;
  int i = cs[p].w;
  float4 v = f[(size_t)i*16 + q];
  size_t ob = (size_t)p*64 + q*4;
  o[ob+0] = f2bf(v.x); o[ob+1] = f2bf(v.y);
  o[ob+2] = f2bf(v.z); o[ob+3] = f2bf(v.w);
}

// W[k][c][d] f32 -> bf16 in MFMA B-fragment order
__global__ void k_wfrag(const float* __restrict__ w, ushort_t* __restrict__ o, int total) {
  int i = blockIdx.x*blockDim.x + threadIdx.x;
  if (i >= total) return;
  int k = i >> 12, r = i & 4095, c = r >> 6, d = r & 63;
  int nt = d >> 4, lp = d & 15, ks = c >> 5, hi = (c >> 3) & 3, e = c & 7;
  int fi = ks*4 + nt, lane = hi*16 + lp;
  o[(size_t)(k*8 + fi)*512 + lane*8 + e] = f2bf(w[i]);
}

__global__ __launch_bounds__(256) void k_up(const ushort_t* __restrict__ featb,
    const ushort_t* __restrict__ wupf, const float* __restrict__ bup,
    ushort_t* __restrict__ y)
{
  int wave = threadIdx.x >> 6, lane = threadIdx.x & 63;
  int n0 = blockIdx.x*64 + wave*16;
  if (n0 >= NPARENT) return;
  int lp = lane & 15, hi = lane >> 4;
  const ushort_t* ar = featb + (size_t)(n0+lp)*64 + hi*8;
  bf16x8 a0 = *(const bf16x8*)(ar);
  bf16x8 a1 = *(const bf16x8*)(ar + 32);
  float bv[4];
  #pragma unroll
  for (int nt=0; nt<4; ++nt) bv[nt] = bup[nt*16+lp];
  for (int c8=0; c8<8; ++c8) {
    const ushort_t* wb = wupf + (size_t)c8*4096 + lane*8;
    f32x4 acc[4];
    #pragma unroll
    for (int nt=0;nt<4;++nt) acc[nt] = (f32x4){0.f,0.f,0.f,0.f};
    #pragma unroll
    for (int nt=0;nt<4;++nt)
      acc[nt] = __builtin_amdgcn_mfma_f32_16x16x32_bf16(a0, *(const bf16x8*)(wb + nt*512), acc[nt], 0,0,0);
    #pragma unroll
    for (int nt=0;nt<4;++nt)
      acc[nt] = __builtin_amdgcn_mfma_f32_16x16x32_bf16(a1, *(const bf16x8*)(wb + (4+nt)*512), acc[nt], 0,0,0);
    #pragma unroll
    for (int nt=0;nt<4;++nt) {
      #pragma unroll
      for (int j=0;j<4;++j) {
        int par = n0 + hi*4 + j;
        float v = acc[nt][j] + bv[nt];
        v = fmaxf(v, 0.f);
        y[(size_t)(par*8 + c8)*64 + nt*16 + lp] = f2bf(v);
      }
    }
  }
}

// sparse stride-1 conv as gather-GEMM over sorted rows. Wave = 64 rows x 64 cols.
// Single global A path (zero-parent for misses), entry table pre-encoded as byte
// bases, 1-iter-deep A prefetch, B 4-deep LDS buffer with barrier per 2 k-iters.
template<int RELU, int SCATTER, typename OUT_T>
__global__ __launch_bounds__(256, 3) void k_conv(const int4* __restrict__ cs,
    const int* __restrict__ tbl, const ushort_t* __restrict__ fin,
    const ushort_t* __restrict__ wf, const float* __restrict__ bias,
    OUT_T* __restrict__ out)
{
  __shared__ __align__(16) int nbt[27*36];           // 144B-padded transposed entries
  __shared__ __align__(16) ushort_t bbuf[4][4096];   // 32KB B quad buffer

  // bijective XCD swizzle: nwg = 1875 = 8*234+3
  int bid = blockIdx.x;
  int xcd = bid & 7, jj = bid >> 3;
  int wg = (xcd < 3 ? xcd*235 : 705 + (xcd-3)*234) + jj;

  int tid = threadIdx.x;
  int wave = tid >> 6, lane = tid & 63;
  int m0 = wg*256 + wave*64;
  int lp = lane & 15, hi = lane >> 4;
  int pblk0 = wg*32;

  // ---- one-time: entry table, transposed + byte-encoded ----
  // storage slot pi = w*8 + h*4 + s  <->  parent = w*8 + s*2 + h
  for (int i = tid; i < 27*32; i += 256) {
    int j = i >> 5, pi = i & 31;
    int w = pi >> 3, h = (pi >> 2) & 1, s = pi & 3;
    int parent = w*8 + s*2 + h;
    int4 cc = cs[pblk0 + parent];
    int dx = j/9 - 1, dy = (j/3)%3 - 1, dz = j%3 - 1;
    int r = tbl[((cc.x+dx+1)*66 + (cc.y+dy+1))*66 + (cc.z+dz+1)];
    nbt[j*36 + pi] = (r < 0 ? NPARENT : r) << 10;
  }

  // ---- stage B for k=0,1 ----
  #pragma unroll
  for (int kk=0; kk<2; ++kk) {
    const char* wb = (const char*)wf + (size_t)kk*8192;
    #pragma unroll
    for (int j2=0;j2<2;++j2) {
      int chunk = wave*2 + j2;
      gl2lds16(wb + chunk*1024 + lane*16, &bbuf[kk][chunk*512]);
    }
  }

  int cx = (lp>>2)&1, cy = (lp>>1)&1, cz = lp&1, c = lp&7;
  int evbase = wave*32 + (lp>>3)*16;                 // byte offset within nbt row
  const char* finl = (const char*)fin + hi*16;

  f32x4 acc[4][4];
  #pragma unroll
  for (int s=0;s<4;++s)
    #pragma unroll
    for (int nt=0;nt<4;++nt) acc[s][nt] = (f32x4){0.f,0.f,0.f,0.f};

  auto prefetch = [&](int k, int* voff, bf16x8* gp) {
    int ox = k/9 - 1, oy = (k/3)%3 - 1, oz = k%3 - 1;
    int xk = ((ox&1)<<2) | ((oy&1)<<1) | (oz&1);
    int cpxoff = (c ^ xk) << 7;
    int idx = ((cx+ox)>>1)*9 + ((cy+oy)>>1)*3 + ((cz+oz)>>1) + 13;
    int4 ev = *(const int4*)((const char*)nbt + idx*144 + evbase);
    voff[0] = ev.x + cpxoff; voff[1] = ev.y + cpxoff;
    voff[2] = ev.z + cpxoff; voff[3] = ev.w + cpxoff;
    #pragma unroll
    for (int s=0;s<4;++s) gp[s] = *(const bf16x8*)(finl + voff[s]);
  };

  auto stage = [&](int k) {   // W(k) -> bbuf[k&3]
    const char* wb = (const char*)wf + (size_t)k*8192;
    #pragma unroll
    for (int j2=0;j2<2;++j2) {
      int chunk = wave*2 + j2;
      gl2lds16(wb + chunk*1024 + lane*16, &bbuf[k&3][chunk*512]);
    }
  };

  auto consume = [&](int k, const int* voff, const bf16x8* gp) {
    const ushort_t* bb = &bbuf[k&3][0];
    bf16x8 g2[4];
    #pragma unroll
    for (int s=0;s<4;++s) g2[s] = *(const bf16x8*)(finl + voff[s] + 64);
    bf16x8 b0[4];
    #pragma unroll
    for (int f=0;f<4;++f) b0[f] = *(const bf16x8*)&bb[f*512 + lane*8];
    #pragma unroll
    for (int s=0;s<4;++s)
      #pragma unroll
      for (int nt=0;nt<4;++nt)
        acc[s][nt] = __builtin_amdgcn_mfma_f32_16x16x32_bf16(gp[s], b0[nt], acc[s][nt], 0,0,0);
    bf16x8 b1[4];
    #pragma unroll
    for (int f=0;f<4;++f) b1[f] = *(const bf16x8*)&bb[(4+f)*512 + lane*8];
    #pragma unroll
    for (int s=0;s<4;++s)
      #pragma unroll
      for (int nt=0;nt<4;++nt)
        acc[s][nt] = __builtin_amdgcn_mfma_f32_16x16x32_bf16(g2[s], b1[nt], acc[s][nt], 0,0,0);
  };

  __syncthreads();   // nbt + bbuf[0..1] ready

  int voffA[4], voffB[4];
  bf16x8 gpA[4], gpB[4];
  prefetch(0, voffA, gpA);

  #pragma unroll 1
  for (int kp = 0; kp < 26; kp += 2) {
    stage(kp+2);                       // kp+2 <= 26 always
    prefetch(kp+1, voffB, gpB);
    consume(kp, voffA, gpA);
    if (kp+3 < 27) stage(kp+3);
    prefetch(kp+2, voffA, gpA);        // consumed after the barrier
    consume(kp+1, voffB, gpB);
    __syncthreads();                   // drains stages; bbuf[kp+2],[kp+3] ready
  }
  consume(26, voffA, gpA);

  float bv[4];
  #pragma unroll
  for (int nt=0;nt<4;++nt) bv[nt] = bias[nt*16+lp];
  #pragma unroll
  for (int s=0;s<4;++s) {
    #pragma unroll
    for (int j=0;j<4;++j) {
      int row = m0 + s*16 + hi*4 + j;
      size_t rb;
      if constexpr (SCATTER) {
        int4 cc = cs[row >> 3];
        rb = ((size_t)cc.w*8 + (row & 7)) * 64;
      } else {
        rb = (size_t)row * 64;
      }
      #pragma unroll
      for (int nt=0;nt<4;++nt) {
        float v = acc[s][nt][j] + bv[nt];
        if (RELU) v = fmaxf(v, 0.f);
        size_t oi = rb + nt*16 + lp;
        if constexpr (sizeof(OUT_T)==2) ((ushort_t*)out)[oi] = f2bf(v);
        else                            out[oi] = v;
      }
    }
  }
}

extern "C" void kernel_launch(void* const* d_in, const int* in_sizes, int n_in,
                              void* d_out, int out_size, void* d_ws, size_t ws_size,
                              hipStream_t stream) {
  const int*   coords = (const int*)d_in[0];
  const float* feats  = (const float*)d_in[1];
  const float* Wup    = (const float*)d_in[2];
  const float* bup    = (const float*)d_in[3];
  const float* W1     = (const float*)d_in[4];
  const float* b1     = (const float*)d_in[5];
  const float* W2     = (const float*)d_in[6];
  const float* b2     = (const float*)d_in[7];
  char* ws = (char*)d_ws;
  if (ws_size < WS_NEED) return;   // fail visibly rather than corrupt

  int*      tbl  = (int*)(ws + OFF_TABLE);
  int4*     cs   = (int4*)(ws + OFF_CS);
  int*      hist = (int*)(ws + OFF_HIST);
  int*      cnt  = (int*)(ws + OFF_CNT);
  ushort_t* y    = (ushort_t*)(ws + OFF_Y);
  ushort_t* z    = (ushort_t*)(ws + OFF_Z);
  ushort_t* fb   = (ushort_t*)(ws + OFF_FEATB);
  ushort_t* wupf = (ushort_t*)(ws + OFF_WUPF);
  ushort_t* w1f  = (ushort_t*)(ws + OFF_W1F);
  ushort_t* w2f  = (ushort_t*)(ws + OFF_W2F);

  hipMemsetAsync(tbl, 0xFF, (size_t)TBL_N*4, stream);
  hipMemsetAsync(hist, 0, (size_t)NBIN*4, stream);
  k_hist<<<(NPARENT+255)/256,256,0,stream>>>(coords, hist);
  k_scan<<<1,256,0,stream>>>(hist, cnt);
  k_rank<<<(NPARENT+255)/256,256,0,stream>>>(coords, cnt, cs, tbl);
  k_zero<<<1,1024,0,stream>>>(y, z);
  k_feats_bf16<<<(NPARENT*16+255)/256,256,0,stream>>>((const float4*)feats, cs, fb, NPARENT*16);
  k_wfrag<<<(8*4096+255)/256,256,0,stream>>>(Wup, wupf, 8*4096);
  k_wfrag<<<(27*4096+255)/256,256,0,stream>>>(W1, w1f, 27*4096);
  k_wfrag<<<(27*4096+255)/256,256,0,stream>>>(W2, w2f, 27*4096);
  k_up<<<(NPARENT+63)/64,256,0,stream>>>(fb, wupf, bup, y);
  k_conv<1,0,ushort_t><<<NOUT/256,256,0,stream>>>(cs, tbl, y,  w1f, b1, z);
  k_conv<0,1,float>   <<<NOUT/256,256,0,stream>>>(cs, tbl, z,  w2f, b2, (float*)d_out);
}